// Round 6
// baseline (2981.101 us; speedup 1.0000x reference)
//
#include <hip/hip_runtime.h>

#define LP  40    // k_support LDS row stride (shorts)
#define LPB 40    // k_main Bs row stride (shorts)

typedef __attribute__((ext_vector_type(8))) short short8;
typedef __attribute__((ext_vector_type(4))) short short4t;
typedef __attribute__((ext_vector_type(4))) float f32x4;

__device__ __forceinline__ short f2bf(float f) {
  unsigned u = __builtin_bit_cast(unsigned, f);
  u += 0x7FFFu + ((u >> 16) & 1u);   // round-to-nearest-even
  return (short)(u >> 16);
}

__device__ __forceinline__ float lrelu(float v) { return v >= 0.f ? v : 0.2f * v; }

// ---------------- Kernel 0: wT bf16 [512][512]  (wt[n][c] = w[c][n]) ----------------
__global__ __launch_bounds__(256) void k_wt(const float* __restrict__ w,
                                            short* __restrict__ wt) {
  __shared__ float t[64][65];
  int c0 = (blockIdx.x & 7) * 64;
  int n0 = (blockIdx.x >> 3) * 64;
  int r  = threadIdx.x >> 4;
  int q4 = (threadIdx.x & 15) * 4;
  for (int i = 0; i < 4; i++) {
    int c = r + i * 16;
    f32x4 v = *(const f32x4*)(w + (size_t)(c0 + c) * 512 + (n0 + q4));
    t[c][q4 + 0] = v[0]; t[c][q4 + 1] = v[1]; t[c][q4 + 2] = v[2]; t[c][q4 + 3] = v[3];
  }
  __syncthreads();
  for (int i = 0; i < 4; i++) {
    int n = r + i * 16;
    short4t o;
    for (int j = 0; j < 4; j++) o[j] = f2bf(t[q4 + j][n]);
    *(short4t*)(wt + (size_t)(n0 + n) * 512 + (c0 + q4)) = o;
  }
}

// ------------- Kernel 1: supportT bf16 [512][8192] = (inputs @ w + b)^T -------------
__global__ __launch_bounds__(512, 2) void k_support(const float* __restrict__ inp,
                                                    const short* __restrict__ wt,
                                                    const float* __restrict__ bias,
                                                    short* __restrict__ sup) {
  __shared__ __align__(16) short As[512 * LP];
  __shared__ __align__(16) short Bs[64 * LP];
  const int tid = threadIdx.x;
  const int m0 = blockIdx.x * 64;
  const int wave = tid >> 6, lane = tid & 63;
  const int wn = wave >> 1, wm = wave & 1;
  const int lr = lane & 15, lk = lane >> 4;
  const int bm = tid >> 3, bk = (tid & 7) * 4;
  f32x4 acc[8][2] = {};
  short8 ar[4]; f32x4 br;
  auto loadA = [&](int s) {
    const short* p = wt + (size_t)tid * 512 + s * 32;
    ar[0] = *(const short8*)(p);      ar[1] = *(const short8*)(p + 8);
    ar[2] = *(const short8*)(p + 16); ar[3] = *(const short8*)(p + 24);
  };
  auto loadB = [&](int s) {
    br = *(const f32x4*)(inp + (size_t)(m0 + bm) * 512 + s * 32 + bk);
  };
  loadA(0); loadB(0);
  for (int s = 0; s < 16; s++) {
    short* ad = As + tid * LP;
    *(short8*)(ad) = ar[0]; *(short8*)(ad + 8) = ar[1];
    *(short8*)(ad + 16) = ar[2]; *(short8*)(ad + 24) = ar[3];
    short4t bo;
    for (int j = 0; j < 4; j++) bo[j] = f2bf(br[j]);
    *(short4t*)(Bs + bm * LP + bk) = bo;
    __syncthreads();
    if (s + 1 < 16) { loadA(s + 1); loadB(s + 1); }
    short8 af[8], bfr[2];
    for (int nf = 0; nf < 8; nf++)
      af[nf] = *(const short8*)(As + (wn * 128 + nf * 16 + lr) * LP + lk * 8);
    for (int mf = 0; mf < 2; mf++)
      bfr[mf] = *(const short8*)(Bs + (wm * 32 + mf * 16 + lr) * LP + lk * 8);
    for (int nf = 0; nf < 8; nf++)
      for (int mf = 0; mf < 2; mf++)
        acc[nf][mf] = __builtin_amdgcn_mfma_f32_16x16x32_bf16(af[nf], bfr[mf], acc[nf][mf], 0, 0, 0);
    __syncthreads();
  }
  for (int nf = 0; nf < 8; nf++) {
    int nb = wn * 128 + nf * 16 + lk * 4;
    for (int mf = 0; mf < 2; mf++) {
      int m = m0 + wm * 32 + mf * 16 + lr;
      for (int j = 0; j < 4; j++) {
        int n = nb + j;
        sup[(size_t)n * 8192 + m] = f2bf(acc[nf][mf][j] + bias[n]);
      }
    }
  }
}

// ---- Kernel 2 (exact R4 revert — fastest so far): BM=64, BN=512, BK=32,
// ---- depth-3 register pipeline.
#define ISSUE(SL, S) {                                                          \
    const float* p_ = abase + (size_t)(S) * 32;                                 \
    R[SL][0] = __builtin_nontemporal_load((const f32x4*)(p_));                  \
    R[SL][1] = __builtin_nontemporal_load((const f32x4*)(p_ + (1ull << 26)));   \
    R[SL][2] = __builtin_nontemporal_load((const f32x4*)(p_ + (2ull << 26)));   \
    R[SL][3] = __builtin_nontemporal_load((const f32x4*)(p_ + (3ull << 26)));   \
  }

#define STEP(U) {                                                               \
    const int s_ = s0 + (U);                                                    \
    if (s_ + 3 < nsteps) ISSUE(((U) + 3) & 3, s_ + 3);                          \
    short8 af[4];                                                               \
    _Pragma("unroll") for (int nf = 0; nf < 4; nf++)                            \
      af[nf] = *(const short8*)(supp + (size_t)(nf * 16) * 8192 + (size_t)s_ * 32); \
    f32x4 c;                                                                    \
    _Pragma("unroll") for (int e = 0; e < 4; e++)                               \
      c[e] = t0 * R[(U)][0][e] + t1 * R[(U)][1][e]                              \
           + t2 * R[(U)][2][e] + t3 * R[(U)][3][e];                             \
    short4t o;                                                                  \
    _Pragma("unroll") for (int e = 0; e < 4; e++) o[e] = f2bf(c[e]);            \
    *(short4t*)(Bs[(U) & 1] + r * LPB + q * 4) = o;                             \
    __syncthreads();                                                            \
    short8 bfr[4];                                                              \
    _Pragma("unroll") for (int mf = 0; mf < 4; mf++)                            \
      bfr[mf] = *(const short8*)(Bs[(U) & 1] + (mf * 16 + lr) * LPB + lk * 8);  \
    _Pragma("unroll") for (int nf = 0; nf < 4; nf++)                            \
      _Pragma("unroll") for (int mf = 0; mf < 4; mf++)                          \
        acc[nf][mf] = __builtin_amdgcn_mfma_f32_16x16x32_bf16(af[nf], bfr[mf],  \
                                                              acc[nf][mf], 0, 0, 0); \
  }

__global__ __launch_bounds__(512, 2) void k_main(const float* __restrict__ adj,
                                                 const float* __restrict__ att,
                                                 const short* __restrict__ sup,
                                                 float* __restrict__ part,
                                                 float* __restrict__ outp,
                                                 int ksplit) {
  __shared__ __align__(16) short Bs[2][64 * LPB];
  const int tid = threadIdx.x;
  const int b = blockIdx.x;
  const int xpk = 8 / ksplit;
  const int xcd = b & 7;
  const int kc = xcd / xpk;
  const int m0 = ((b >> 3) * xpk + (xcd % xpk)) * 64;
  const int kchunk = 8192 / ksplit;
  const int nsteps = kchunk / 32;
  const int kbase = kc * kchunk;
  const float t0 = att[0], t1 = att[1], t2 = att[2], t3 = att[3];
  const int wave = tid >> 6, lane = tid & 63;
  const int lr = lane & 15, lk = lane >> 4;
  const int r = tid >> 3, q = tid & 7;
  f32x4 acc[4][4] = {};
  const float* abase = adj + (size_t)(m0 + r) * 8192 + kbase + q * 4;
  const short* supp = sup + (size_t)(wave * 64 + lr) * 8192 + kbase + lk * 8;
  f32x4 R[4][4];

  ISSUE(0, 0); ISSUE(1, 1); ISSUE(2, 2);
  for (int s0 = 0; s0 < nsteps; s0 += 4) {
    STEP(0) STEP(1) STEP(2) STEP(3)
  }

#pragma unroll
  for (int nf = 0; nf < 4; nf++) {
    int n = wave * 64 + nf * 16 + lk * 4;
#pragma unroll
    for (int mf = 0; mf < 4; mf++) {
      int m = m0 + mf * 16 + lr;
      f32x4 v = acc[nf][mf];
      if (ksplit == 1) {
        for (int j = 0; j < 4; j++) v[j] = lrelu(v[j]);
        __builtin_nontemporal_store(v, (f32x4*)(outp + (size_t)m * 512 + n));
      } else {
        __builtin_nontemporal_store(v, (f32x4*)(part + ((size_t)kc << 22) + (size_t)m * 512 + n));
      }
    }
  }
}

// ---------------- Kernel 3: reduce K-split partials + LeakyReLU ----------------
__global__ __launch_bounds__(256) void k_reduce(const float* __restrict__ part,
                                                float* __restrict__ outp, int ksplit) {
  const size_t total = (size_t)8192 * 512 / 4;
  for (size_t i = (size_t)blockIdx.x * 256 + threadIdx.x; i < total;
       i += (size_t)gridDim.x * 256) {
    f32x4 a = __builtin_nontemporal_load((const f32x4*)(part + i * 4));
    for (int k = 1; k < ksplit; k++) {
      f32x4 bv = __builtin_nontemporal_load((const f32x4*)(part + ((size_t)k << 22) + i * 4));
      for (int j = 0; j < 4; j++) a[j] += bv[j];
    }
    f32x4 v;
    for (int j = 0; j < 4; j++) v[j] = lrelu(a[j]);
    __builtin_nontemporal_store(v, (f32x4*)(outp + i * 4));
  }
}

// ================= DIAGNOSTIC PROBES (results -> scratch, overwritten info) ========
// P1: perfectly linear read of adj. 256 blocks x 1024 thr, 4 MiB contiguous slab
// per block, 5 passes (~850 us total) -> true READ ceiling of this buffer.
__global__ __launch_bounds__(1024) void p_linear(const float* __restrict__ adj,
                                                 float* __restrict__ sink) {
  const size_t slab = (size_t)blockIdx.x << 20;   // 2^20 floats
  float s = 0.f;
  for (int pass = 0; pass < 5; pass++) {
    for (int i = threadIdx.x * 4; i < (1 << 20); i += 1024 * 4) {
      f32x4 v = *(const f32x4*)(adj + slab + i);
      s += v[0] + v[1] + v[2] + v[3];
    }
  }
  sink[(size_t)blockIdx.x * 1024 + threadIdx.x] = s;
}

// P2/P3: k_main's exact adj stream (loads only). skew=0 -> exact pattern.
// skew=1024 -> the 4 mats' k-offsets shifted 4 KB apart (breaks any DRAM
// channel/bank aliasing of the 4 streams at exactly 2^28 B stride). 3 passes.
__global__ __launch_bounds__(512) void p_pat(const float* __restrict__ adj,
                                             float* __restrict__ sink, int skew) {
  const int b = blockIdx.x;
  const int xcd = b & 7;
  const int kc = xcd >> 2;
  const int m0 = ((b >> 3) * 4 + (xcd & 3)) * 64;
  const int kbase = kc * 4096;
  const int r = threadIdx.x >> 3, q = threadIdx.x & 7;
  const float* base = adj + (size_t)(m0 + r) * 8192 + kbase + q * 4;
  float s = 0.f;
  for (int pass = 0; pass < 3; pass++) {
    for (int st = 0; st < 128; st++) {
#pragma unroll
      for (int mat = 0; mat < 4; mat++) {
        int ke = (st * 32 + mat * skew) & 4095;
        f32x4 v = __builtin_nontemporal_load(
            (const f32x4*)(base + ((size_t)mat << 26) + ke));
        s += v[0] + v[1] + v[2] + v[3];
      }
    }
  }
  sink[(size_t)b * 512 + threadIdx.x] = s;
}

// P4: P2 + the sup fragment loads (k_main's FULL load mix, no LDS/MFMA/barriers).
// Tests per-CU L2/VMEM-path contention between adj stream and af stream. 3 passes.
__global__ __launch_bounds__(512) void p_pat_af(const float* __restrict__ adj,
                                                const short* __restrict__ sup,
                                                float* __restrict__ sink) {
  const int b = blockIdx.x;
  const int xcd = b & 7;
  const int kc = xcd >> 2;
  const int m0 = ((b >> 3) * 4 + (xcd & 3)) * 64;
  const int kbase = kc * 4096;
  const int r = threadIdx.x >> 3, q = threadIdx.x & 7;
  const int wave = threadIdx.x >> 6, lane = threadIdx.x & 63;
  const int lr = lane & 15, lk = lane >> 4;
  const float* base = adj + (size_t)(m0 + r) * 8192 + kbase + q * 4;
  const float* supp = (const float*)(sup + (size_t)(wave * 64 + lr) * 8192 + kbase + lk * 8);
  float s = 0.f;
  for (int pass = 0; pass < 3; pass++) {
    for (int st = 0; st < 128; st++) {
#pragma unroll
      for (int mat = 0; mat < 4; mat++) {
        f32x4 v = __builtin_nontemporal_load(
            (const f32x4*)(base + ((size_t)mat << 26) + st * 32));
        s += v[0] + v[1] + v[2] + v[3];
      }
#pragma unroll
      for (int nf = 0; nf < 4; nf++) {
        f32x4 v = *(const f32x4*)(supp + ((size_t)(nf * 16) * 8192 + st * 32) / 2);
        s += v[0] + v[1] + v[2] + v[3];
      }
    }
  }
  sink[(size_t)b * 512 + threadIdx.x] = s;
}

extern "C" void kernel_launch(void* const* d_in, const int* in_sizes, int n_in,
                              void* d_out, int out_size, void* d_ws, size_t ws_size,
                              hipStream_t stream) {
  const float* inputs = (const float*)d_in[0];
  const float* adj    = (const float*)d_in[1];
  const float* att    = (const float*)d_in[2];
  const float* w      = (const float*)d_in[3];
  const float* bias   = (const float*)d_in[4];
  float* outp = (float*)d_out;

  char* ws = (char*)d_ws;
  short* sup  = (short*)(ws);                 // 8 MB  supportT bf16 [512][8192]
  short* wt   = (short*)(ws + (8u << 20));    // 512 KB wT bf16 [512][512]
  float* part = (float*)(ws + (9u << 20));    // ksplit x 16 MB fp32 partials

  const size_t base = (9ull << 20), psz = (1ull << 24);
  int ksplit = (ws_size >= base + 2 * psz) ? 2 : 1;

  k_wt<<<64, 256, 0, stream>>>(w, wt);
  k_support<<<128, 512, 0, stream>>>(inputs, wt, bias, sup);
  k_main<<<128 * ksplit, 512, 0, stream>>>(adj, att, sup, part, outp, ksplit);
  if (ksplit > 1) k_reduce<<<1024, 256, 0, stream>>>(part, outp, ksplit);

  // ---- diagnostic probes (after the real pipeline; write only to scratch) ----
  float* sink = part;   // overwritten scratch, d_out already final
  p_linear<<<256, 1024, 0, stream>>>(adj, sink);
  p_pat<<<256, 512, 0, stream>>>(adj, sink, 0);       // exact k_main adj pattern
  p_pat<<<256, 512, 0, stream>>>(adj, sink, 1024);    // mat-skewed variant
  p_pat_af<<<256, 512, 0, stream>>>(adj, sup, sink);  // pattern + sup fragments
}

// Round 7
// 308.085 us; speedup vs baseline: 9.6762x; 9.6762x over previous
//
#include <hip/hip_runtime.h>

#define LP  40    // k_support LDS row stride (shorts)
#define LPB 40    // k_main Bs row stride (shorts)

typedef __attribute__((ext_vector_type(8))) short short8;
typedef __attribute__((ext_vector_type(4))) short short4t;
typedef __attribute__((ext_vector_type(4))) float f32x4;

__device__ __forceinline__ short f2bf(float f) {
  unsigned u = __builtin_bit_cast(unsigned, f);
  u += 0x7FFFu + ((u >> 16) & 1u);   // round-to-nearest-even
  return (short)(u >> 16);
}

__device__ __forceinline__ float lrelu(float v) { return v >= 0.f ? v : 0.2f * v; }

// ---------------- Kernel 0: wT bf16 [512][512]  (wt[n][c] = w[c][n]) ----------------
__global__ __launch_bounds__(256) void k_wt(const float* __restrict__ w,
                                            short* __restrict__ wt) {
  __shared__ float t[64][65];
  int c0 = (blockIdx.x & 7) * 64;
  int n0 = (blockIdx.x >> 3) * 64;
  int r  = threadIdx.x >> 4;
  int q4 = (threadIdx.x & 15) * 4;
  for (int i = 0; i < 4; i++) {
    int c = r + i * 16;
    f32x4 v = *(const f32x4*)(w + (size_t)(c0 + c) * 512 + (n0 + q4));
    t[c][q4 + 0] = v[0]; t[c][q4 + 1] = v[1]; t[c][q4 + 2] = v[2]; t[c][q4 + 3] = v[3];
  }
  __syncthreads();
  for (int i = 0; i < 4; i++) {
    int n = r + i * 16;
    short4t o;
    for (int j = 0; j < 4; j++) o[j] = f2bf(t[q4 + j][n]);
    *(short4t*)(wt + (size_t)(n0 + n) * 512 + (c0 + q4)) = o;
  }
}

// ------------- Kernel 1: supportT bf16 [512][8192] = (inputs @ w + b)^T -------------
__global__ __launch_bounds__(512, 2) void k_support(const float* __restrict__ inp,
                                                    const short* __restrict__ wt,
                                                    const float* __restrict__ bias,
                                                    short* __restrict__ sup) {
  __shared__ __align__(16) short As[512 * LP];
  __shared__ __align__(16) short Bs[64 * LP];
  const int tid = threadIdx.x;
  const int m0 = blockIdx.x * 64;
  const int wave = tid >> 6, lane = tid & 63;
  const int wn = wave >> 1, wm = wave & 1;
  const int lr = lane & 15, lk = lane >> 4;
  const int bm = tid >> 3, bk = (tid & 7) * 4;
  f32x4 acc[8][2] = {};
  short8 ar[4]; f32x4 br;
  auto loadA = [&](int s) {
    const short* p = wt + (size_t)tid * 512 + s * 32;
    ar[0] = *(const short8*)(p);      ar[1] = *(const short8*)(p + 8);
    ar[2] = *(const short8*)(p + 16); ar[3] = *(const short8*)(p + 24);
  };
  auto loadB = [&](int s) {
    br = *(const f32x4*)(inp + (size_t)(m0 + bm) * 512 + s * 32 + bk);
  };
  loadA(0); loadB(0);
  for (int s = 0; s < 16; s++) {
    short* ad = As + tid * LP;
    *(short8*)(ad) = ar[0]; *(short8*)(ad + 8) = ar[1];
    *(short8*)(ad + 16) = ar[2]; *(short8*)(ad + 24) = ar[3];
    short4t bo;
    for (int j = 0; j < 4; j++) bo[j] = f2bf(br[j]);
    *(short4t*)(Bs + bm * LP + bk) = bo;
    __syncthreads();
    if (s + 1 < 16) { loadA(s + 1); loadB(s + 1); }
    short8 af[8], bfr[2];
    for (int nf = 0; nf < 8; nf++)
      af[nf] = *(const short8*)(As + (wn * 128 + nf * 16 + lr) * LP + lk * 8);
    for (int mf = 0; mf < 2; mf++)
      bfr[mf] = *(const short8*)(Bs + (wm * 32 + mf * 16 + lr) * LP + lk * 8);
    for (int nf = 0; nf < 8; nf++)
      for (int mf = 0; mf < 2; mf++)
        acc[nf][mf] = __builtin_amdgcn_mfma_f32_16x16x32_bf16(af[nf], bfr[mf], acc[nf][mf], 0, 0, 0);
    __syncthreads();
  }
  for (int nf = 0; nf < 8; nf++) {
    int nb = wn * 128 + nf * 16 + lk * 4;
    for (int mf = 0; mf < 2; mf++) {
      int m = m0 + wm * 32 + mf * 16 + lr;
      for (int j = 0; j < 4; j++) {
        int n = nb + j;
        sup[(size_t)n * 8192 + m] = f2bf(acc[nf][mf][j] + bias[n]);
      }
    }
  }
}

// ---- Kernel 2: BM=64, BN=512, BK=32. R4 skeleton + drain-free barrier:
// ---- raw s_barrier with lgkmcnt(0) ONLY (no __syncthreads -> no vmcnt(0) drain),
// ---- distance-2 adj prefetch (4 slots) + distance-1 af prefetch (2 slots),
// ---- counted vmcnt pacing, wrap-around dummy issues for uniform counts.
#define ISSUE(SL, S) {                                                          \
    const float* p_ = abase + (size_t)(S) * 32;                                 \
    R[SL][0] = __builtin_nontemporal_load((const f32x4*)(p_));                  \
    R[SL][1] = __builtin_nontemporal_load((const f32x4*)(p_ + (1ull << 26)));   \
    R[SL][2] = __builtin_nontemporal_load((const f32x4*)(p_ + (2ull << 26)));   \
    R[SL][3] = __builtin_nontemporal_load((const f32x4*)(p_ + (3ull << 26)));   \
  }

#define ISSUEAF(SL, S) {                                                        \
    const short* q_ = supp + (size_t)(S) * 32;                                  \
    AF[SL][0] = *(const short8*)(q_);                                           \
    AF[SL][1] = *(const short8*)(q_ + (size_t)16 * 8192);                       \
    AF[SL][2] = *(const short8*)(q_ + (size_t)32 * 8192);                       \
    AF[SL][3] = *(const short8*)(q_ + (size_t)48 * 8192);                       \
  }

#define STEP(U) {                                                               \
    ISSUE(((U) + 2) & 3, (s0 + (U) + 2) & (nsteps - 1))                         \
    ISSUEAF(((U) + 1) & 1, (s0 + (U) + 1) & (nsteps - 1))                       \
    __builtin_amdgcn_sched_barrier(0);                                          \
    asm volatile("s_waitcnt vmcnt(20)" ::: "memory");                           \
    __builtin_amdgcn_sched_barrier(0);                                          \
    f32x4 c_;                                                                   \
    _Pragma("unroll") for (int e = 0; e < 4; e++)                               \
      c_[e] = t0 * R[(U) & 3][0][e] + t1 * R[(U) & 3][1][e]                     \
            + t2 * R[(U) & 3][2][e] + t3 * R[(U) & 3][3][e];                    \
    short4t o_;                                                                 \
    _Pragma("unroll") for (int e = 0; e < 4; e++) o_[e] = f2bf(c_[e]);          \
    *(short4t*)(Bs[(U) & 1] + r * LPB + q * 4) = o_;                            \
    asm volatile("s_waitcnt lgkmcnt(0)" ::: "memory");                          \
    __builtin_amdgcn_sched_barrier(0);                                          \
    __builtin_amdgcn_s_barrier();                                               \
    __builtin_amdgcn_sched_barrier(0);                                          \
    short8 bfr[4];                                                              \
    _Pragma("unroll") for (int mf = 0; mf < 4; mf++)                            \
      bfr[mf] = *(const short8*)(Bs[(U) & 1] + (mf * 16 + lr) * LPB + lk * 8);  \
    asm volatile("s_waitcnt vmcnt(8)" ::: "memory");                            \
    __builtin_amdgcn_sched_barrier(0);                                          \
    _Pragma("unroll") for (int nf = 0; nf < 4; nf++)                            \
      _Pragma("unroll") for (int mf = 0; mf < 4; mf++)                          \
        acc[nf][mf] = __builtin_amdgcn_mfma_f32_16x16x32_bf16(AF[(U) & 1][nf],  \
                          bfr[mf], acc[nf][mf], 0, 0, 0);                       \
  }

__global__ __launch_bounds__(512, 2) void k_main(const float* __restrict__ adj,
                                                 const float* __restrict__ att,
                                                 const short* __restrict__ sup,
                                                 float* __restrict__ part,
                                                 float* __restrict__ outp,
                                                 int ksplit) {
  __shared__ __align__(16) short Bs[2][64 * LPB];
  const int tid = threadIdx.x;
  const int b = blockIdx.x;
  const int xpk = 8 / ksplit;
  const int xcd = b & 7;
  const int kc = xcd / xpk;                 // kc pinned per XCD group -> sup L2-warm
  const int m0 = ((b >> 3) * xpk + (xcd % xpk)) * 64;
  const int kchunk = 8192 / ksplit;
  const int nsteps = kchunk / 32;           // 128 at ksplit=2 (pow2)
  const int kbase = kc * kchunk;
  const float t0 = att[0], t1 = att[1], t2 = att[2], t3 = att[3];
  const int wave = tid >> 6, lane = tid & 63;
  const int lr = lane & 15, lk = lane >> 4;
  const int r = tid >> 3, q = tid & 7;      // combine map: row 0..63, 16B-octant
  f32x4 acc[4][4] = {};                     // [nf][mf]
  const float* abase = adj + (size_t)(m0 + r) * 8192 + kbase + q * 4;
  const short* supp = sup + (size_t)(wave * 64 + lr) * 8192 + kbase + lk * 8;
  f32x4 R[4][4];                            // adj slots (distance 2)
  short8 AF[2][4];                          // sup slots (distance 1)

  ISSUE(0, 0) ISSUEAF(0, 0) ISSUE(1, 1)
  for (int s0 = 0; s0 < nsteps; s0 += 4) {
    STEP(0) STEP(1) STEP(2) STEP(3)
  }

#pragma unroll
  for (int nf = 0; nf < 4; nf++) {
    int n = wave * 64 + nf * 16 + lk * 4;
#pragma unroll
    for (int mf = 0; mf < 4; mf++) {
      int m = m0 + mf * 16 + lr;
      f32x4 v = acc[nf][mf];
      if (ksplit == 1) {
        for (int j = 0; j < 4; j++) v[j] = lrelu(v[j]);
        __builtin_nontemporal_store(v, (f32x4*)(outp + (size_t)m * 512 + n));
      } else {
        __builtin_nontemporal_store(v, (f32x4*)(part + ((size_t)kc << 22) + (size_t)m * 512 + n));
      }
    }
  }
}

// ---------------- Kernel 3: reduce K-split partials + LeakyReLU ----------------
__global__ __launch_bounds__(256) void k_reduce(const float* __restrict__ part,
                                                float* __restrict__ outp, int ksplit) {
  const size_t total = (size_t)8192 * 512 / 4;
  for (size_t i = (size_t)blockIdx.x * 256 + threadIdx.x; i < total;
       i += (size_t)gridDim.x * 256) {
    f32x4 a = __builtin_nontemporal_load((const f32x4*)(part + i * 4));
    for (int k = 1; k < ksplit; k++) {
      f32x4 bv = __builtin_nontemporal_load((const f32x4*)(part + ((size_t)k << 22) + i * 4));
      for (int j = 0; j < 4; j++) a[j] += bv[j];
    }
    f32x4 v;
    for (int j = 0; j < 4; j++) v[j] = lrelu(a[j]);
    __builtin_nontemporal_store(v, (f32x4*)(outp + i * 4));
  }
}

extern "C" void kernel_launch(void* const* d_in, const int* in_sizes, int n_in,
                              void* d_out, int out_size, void* d_ws, size_t ws_size,
                              hipStream_t stream) {
  const float* inputs = (const float*)d_in[0];
  const float* adj    = (const float*)d_in[1];
  const float* att    = (const float*)d_in[2];
  const float* w      = (const float*)d_in[3];
  const float* bias   = (const float*)d_in[4];
  float* outp = (float*)d_out;

  char* ws = (char*)d_ws;
  short* sup  = (short*)(ws);                 // 8 MB  supportT bf16 [512][8192]
  short* wt   = (short*)(ws + (8u << 20));    // 512 KB wT bf16 [512][512]
  float* part = (float*)(ws + (9u << 20));    // ksplit x 16 MB fp32 partials

  const size_t base = (9ull << 20), psz = (1ull << 24);
  int ksplit = (ws_size >= base + 2 * psz) ? 2 : 1;

  k_wt<<<64, 256, 0, stream>>>(w, wt);
  k_support<<<128, 512, 0, stream>>>(inputs, wt, bias, sup);
  k_main<<<128 * ksplit, 512, 0, stream>>>(adj, att, sup, part, outp, ksplit);
  if (ksplit > 1) k_reduce<<<1024, 256, 0, stream>>>(part, outp, ksplit);
}